// Round 1
// baseline (858.840 us; speedup 1.0000x reference)
//
#include <hip/hip_runtime.h>
#include <hip/hip_bf16.h>
#include <stdint.h>

typedef unsigned short u16;
typedef __attribute__((ext_vector_type(8))) short short8;
typedef __attribute__((ext_vector_type(4))) float f32x4;
typedef __attribute__((ext_vector_type(4))) unsigned short u16x4;

constexpr int BB = 2, SS = 2048, HSZ = 2048, NH = 16, NKV = 4, DH = 128;
constexpr int MROWS = BB * SS;             // 4096
constexpr int NQKV = (NH + 2 * NKV) * DH;  // 3072
constexpr float RMS_EPS = 1e-6f;

__device__ __forceinline__ u16 f2bf(float f) {
  __hip_bfloat16 h = __float2bfloat16(f);
  return *reinterpret_cast<u16*>(&h);
}
__device__ __forceinline__ float bf2f(u16 u) {
  __hip_bfloat16 h;
  *reinterpret_cast<u16*>(&h) = u;
  return __bfloat162float(h);
}

__device__ __forceinline__ void gld16(const void* g, void* l) {
  __builtin_amdgcn_global_load_lds(
      (const __attribute__((address_space(1))) void*)g,
      (__attribute__((address_space(3))) void*)l, 16, 0, 0);
}

// ---------------- fp32 -> bf16 conversion (vectorized) ----------------
__global__ void cvt_bf16_kernel(const float* __restrict__ in, u16* __restrict__ out, int n4) {
  int i = blockIdx.x * blockDim.x + threadIdx.x;
  if (i >= n4) return;
  float4 v = reinterpret_cast<const float4*>(in)[i];
  u16x4 o;
  o.x = f2bf(v.x); o.y = f2bf(v.y); o.z = f2bf(v.z); o.w = f2bf(v.w);
  reinterpret_cast<u16x4*>(out)[i] = o;
}

// ---------------- GEMM: C[M][N] = A[M][K] @ B[N][K]^T (bf16 in, OutT out) ----
// m97 structure: 128x128 tile, BK=32, 4 waves (2x2), global_load_lds width 16.
template <typename OutT>
__global__ __launch_bounds__(256, 2) void gemm_bt(
    const u16* __restrict__ A, const u16* __restrict__ Bm, OutT* __restrict__ C,
    int M, int N, int K, int nbn) {
  __shared__ u16 As[128 * 32];
  __shared__ u16 Bs[128 * 32];
  const int tid = threadIdx.x;
  const int wave = tid >> 6;
  const int lane = tid & 63;
  const int bid = blockIdx.x;
  const int bm = bid / nbn, bn = bid % nbn;
  const int row0 = bm * 128, col0 = bn * 128;
  const int wr = (wave >> 1) * 64, wc = (wave & 1) * 64;
  const int lr = lane & 15, lk = (lane >> 4) * 8;
  const int sr = tid >> 2;        // staging row (0..63) within half-tile
  const int sc = (tid & 3) * 8;   // staging col (elements)

  f32x4 acc[4][4] = {};
  const u16* a0 = A + (size_t)(row0 + sr) * K + sc;
  const u16* a1 = A + (size_t)(row0 + 64 + sr) * K + sc;
  const u16* b0 = Bm + (size_t)(col0 + sr) * K + sc;
  const u16* b1 = Bm + (size_t)(col0 + 64 + sr) * K + sc;
  char* asb = (char*)As + wave * 1024;
  char* bsb = (char*)Bs + wave * 1024;

  for (int k0 = 0; k0 < K; k0 += 32) {
    __syncthreads();
    gld16(a0 + k0, asb);
    gld16(a1 + k0, asb + 4096);
    gld16(b0 + k0, bsb);
    gld16(b1 + k0, bsb + 4096);
    __syncthreads();
    short8 af[4], bfr[4];
#pragma unroll
    for (int m = 0; m < 4; m++)
      af[m] = *(const short8*)&As[(wr + m * 16 + lr) * 32 + lk];
#pragma unroll
    for (int n = 0; n < 4; n++)
      bfr[n] = *(const short8*)&Bs[(wc + n * 16 + lr) * 32 + lk];
#pragma unroll
    for (int m = 0; m < 4; m++)
#pragma unroll
      for (int n = 0; n < 4; n++)
        acc[m][n] = __builtin_amdgcn_mfma_f32_16x16x32_bf16(af[m], bfr[n], acc[m][n], 0, 0, 0);
  }
  const int cr = (lane >> 4) * 4, cc = lane & 15;
#pragma unroll
  for (int m = 0; m < 4; m++) {
#pragma unroll
    for (int n = 0; n < 4; n++) {
#pragma unroll
      for (int r = 0; r < 4; r++) {
        size_t idx = (size_t)(row0 + wr + m * 16 + cr + r) * N + (col0 + wc + n * 16 + cc);
        if constexpr (sizeof(OutT) == 2) C[idx] = (OutT)f2bf(acc[m][n][r]);
        else C[idx] = acc[m][n][r];
      }
    }
  }
}

// ---------------- RMS-norm (q,k heads) + RoPE + split/cast --------------------
// One block per (b,s) row of C_qkv[4096][3072]; wave handles heads wave,wave+4,...
__global__ __launch_bounds__(256) void postproc_kernel(
    const u16* __restrict__ Cqkv, const float* __restrict__ cosT,
    const float* __restrict__ sinT, const float* __restrict__ qw,
    const float* __restrict__ kw, u16* __restrict__ qO, u16* __restrict__ kO,
    u16* __restrict__ vO) {
  const int row = blockIdx.x;
  const int b = row / SS, s = row % SS;
  const int wave = threadIdx.x >> 6, lane = threadIdx.x & 63;
  const u16* base = Cqkv + (size_t)row * NQKV;
  const int d0 = lane * 2;
  for (int hd = wave; hd < NH + 2 * NKV; hd += 4) {
    const u16* hp = base + hd * DH;
    ushort2 raw = *(const ushort2*)(hp + d0);
    if (hd < NH + NKV) {
      float v0 = bf2f(raw.x), v1 = bf2f(raw.y);
      float ss = v0 * v0 + v1 * v1;
#pragma unroll
      for (int off = 32; off > 0; off >>= 1) ss += __shfl_xor(ss, off);
      float inv = rsqrtf(ss * (1.0f / DH) + RMS_EPS);
      const float* w = (hd < NH) ? qw : kw;
      float n0 = v0 * inv * w[d0], n1 = v1 * inv * w[d0 + 1];
      // rotate_half: lane<32 holds d<64, partner lane^32 holds d^64
      float r0 = __shfl_xor(n0, 32), r1 = __shfl_xor(n1, 32);
      float sgn = (lane < 32) ? -1.f : 1.f;
      float c0 = cosT[s * DH + d0], c1 = cosT[s * DH + d0 + 1];
      float s0 = sinT[s * DH + d0], s1 = sinT[s * DH + d0 + 1];
      ushort2 o;
      o.x = f2bf(n0 * c0 + sgn * r0 * s0);
      o.y = f2bf(n1 * c1 + sgn * r1 * s1);
      if (hd < NH)
        *(ushort2*)(qO + ((size_t)((b * NH + hd) * SS + s)) * DH + d0) = o;
      else
        *(ushort2*)(kO + ((size_t)((b * NKV + hd - NH) * SS + s)) * DH + d0) = o;
    } else {
      *(ushort2*)(vO + ((size_t)((b * NKV + hd - NH - NKV) * SS + s)) * DH + d0) = raw;
    }
  }
}

// ---------------- V transpose: [b,hkv][S][D] -> [b,hkv][D][S] ----------------
__global__ __launch_bounds__(256) void transpose_v_kernel(const u16* __restrict__ v,
                                                          u16* __restrict__ vt) {
  __shared__ u16 tile[64][68];  // pad to 68 for bank spread + 8B alignment
  const int bh = blockIdx.z;
  const int st = blockIdx.x * 64;
  const int dt = blockIdx.y * 64;
  const int tid = threadIdx.x;
  const u16* src = v + ((size_t)bh * SS + st) * DH + dt;
#pragma unroll
  for (int it = 0; it < 4; it++) {
    int r = (tid >> 4) + it * 16, c = (tid & 15) * 4;
    *(u16x4*)&tile[r][c] = *(const u16x4*)(src + (size_t)r * DH + c);
  }
  __syncthreads();
  u16* dst = vt + ((size_t)bh * DH + dt) * SS + st;
#pragma unroll
  for (int it = 0; it < 4; it++) {
    int r2 = (tid >> 4) + it * 16, c2 = (tid & 15) * 4;
    u16x4 o;
    o.x = tile[c2][r2]; o.y = tile[c2 + 1][r2];
    o.z = tile[c2 + 2][r2]; o.w = tile[c2 + 3][r2];
    *(u16x4*)(dst + (size_t)r2 * SS + c2) = o;
  }
}

// ---------------- causal GQA flash attention ---------------------------------
// grid (S/64, H, B); 4 waves; wave owns 16 q-rows; KV tiles of 64.
// K read direct from global (L2-resident), V pre-transposed [D][S].
__global__ __launch_bounds__(256, 2) void attn_kernel(
    const u16* __restrict__ Q, const u16* __restrict__ Kb,
    const u16* __restrict__ Vt, u16* __restrict__ O) {
  __shared__ u16 Plds[4][16 * 72];  // per-wave P transpose buffer (stride 72)
  const int qt = blockIdx.x, h = blockIdx.y, b = blockIdx.z;
  const int hkv = h >> 2;
  const int wave = threadIdx.x >> 6, lane = threadIdx.x & 63;
  const int q0 = qt * 64 + wave * 16;
  const int lr = lane & 15, lk = lane >> 4;
  const u16* qbase = Q + ((size_t)(b * NH + h) * SS) * DH;
  const u16* kbase = Kb + ((size_t)(b * NKV + hkv) * SS) * DH;
  const u16* vbase = Vt + ((size_t)(b * NKV + hkv) * DH) * SS;

  short8 qf[4];
#pragma unroll
  for (int c = 0; c < 4; c++)
    qf[c] = *(const short8*)(qbase + (size_t)(q0 + lr) * DH + c * 32 + lk * 8);

  f32x4 o_acc[8] = {};
  float m_run[4], l_run[4];
#pragma unroll
  for (int r = 0; r < 4; r++) { m_run[r] = -1e30f; l_run[r] = 0.f; }

  const float scale = 0.08838834764831843f;  // D^-0.5
  const int kv_hi = q0 + 16;                 // wave causal end (exclusive)
  u16* pl = &Plds[wave][0];

  for (int kv0 = 0; kv0 < kv_hi; kv0 += 64) {
    // ---- QK^T: S[16 q][64 kv] ----
    f32x4 sf[4] = {};
#pragma unroll
    for (int n = 0; n < 4; n++) {
#pragma unroll
      for (int c = 0; c < 4; c++) {
        short8 kf = *(const short8*)(kbase + (size_t)(kv0 + n * 16 + lr) * DH + c * 32 + lk * 8);
        sf[n] = __builtin_amdgcn_mfma_f32_16x16x32_bf16(qf[c], kf, sf[n], 0, 0, 0);
      }
    }
    // ---- online softmax (C-frag: row = lk*4+r, col = n*16+lr) ----
    const int qrow = q0 + lk * 4;
    float p[4][4];
#pragma unroll
    for (int r = 0; r < 4; r++) {
      float mx = -1e30f;
#pragma unroll
      for (int n = 0; n < 4; n++) {
        float sv = sf[n][r] * scale;
        sv = (kv0 + n * 16 + lr <= qrow + r) ? sv : -1e30f;
        p[n][r] = sv;
        mx = fmaxf(mx, sv);
      }
      mx = fmaxf(mx, __shfl_xor(mx, 1));
      mx = fmaxf(mx, __shfl_xor(mx, 2));
      mx = fmaxf(mx, __shfl_xor(mx, 4));
      mx = fmaxf(mx, __shfl_xor(mx, 8));
      const float mnew = fmaxf(m_run[r], mx);
      const float alpha = __expf(m_run[r] - mnew);
      m_run[r] = mnew;
      float rs = 0.f;
#pragma unroll
      for (int n = 0; n < 4; n++) {
        float e = __expf(p[n][r] - mnew);
        p[n][r] = e;
        rs += e;
      }
      rs += __shfl_xor(rs, 1);
      rs += __shfl_xor(rs, 2);
      rs += __shfl_xor(rs, 4);
      rs += __shfl_xor(rs, 8);
      l_run[r] = l_run[r] * alpha + rs;
#pragma unroll
      for (int n2 = 0; n2 < 8; n2++) o_acc[n2][r] *= alpha;
    }
    // ---- P: C-layout -> A-layout via wave-private LDS ----
#pragma unroll
    for (int r = 0; r < 4; r++)
#pragma unroll
      for (int n = 0; n < 4; n++)
        pl[(lk * 4 + r) * 72 + n * 16 + lr] = f2bf(p[n][r]);
    // ---- PV: O[16 q][128 d] += P[16][64] @ V[64][128] ----
#pragma unroll
    for (int c2 = 0; c2 < 2; c2++) {
      short8 pf = *(const short8*)&pl[lr * 72 + c2 * 32 + lk * 8];
#pragma unroll
      for (int n2 = 0; n2 < 8; n2++) {
        short8 vf = *(const short8*)(vbase + (size_t)(n2 * 16 + lr) * SS + kv0 + c2 * 32 + lk * 8);
        o_acc[n2] = __builtin_amdgcn_mfma_f32_16x16x32_bf16(pf, vf, o_acc[n2], 0, 0, 0);
      }
    }
  }
  // ---- epilogue: normalize, write O[b][s][h*128+d] bf16 ----
  const int cr = lk * 4;
#pragma unroll
  for (int r = 0; r < 4; r++) {
    const float inv = 1.0f / l_run[r];
    u16* orow = O + ((size_t)(b * SS + q0 + cr + r)) * (NH * DH) + h * DH;
#pragma unroll
    for (int n2 = 0; n2 < 8; n2++) orow[n2 * 16 + lr] = f2bf(o_acc[n2][r] * inv);
  }
}

// -----------------------------------------------------------------------------
extern "C" void kernel_launch(void* const* d_in, const int* in_sizes, int n_in,
                              void* d_out, int out_size, void* d_ws, size_t ws_size,
                              hipStream_t stream) {
  const float* x    = (const float*)d_in[0];
  const float* cosT = (const float*)d_in[1];
  const float* sinT = (const float*)d_in[2];
  // d_in[3] = mask (causal, reconstructed analytically)
  const float* wq = (const float*)d_in[4];
  const float* wk = (const float*)d_in[5];
  const float* wv = (const float*)d_in[6];
  const float* wo = (const float*)d_in[7];
  const float* qw = (const float*)d_in[8];
  const float* kw = (const float*)d_in[9];
  float* out = (float*)d_out;

  char* p = (char*)d_ws;
  u16* xb    = (u16*)p; p += (size_t)MROWS * HSZ * 2;
  u16* wqkvb = (u16*)p; p += (size_t)NQKV * HSZ * 2;
  u16* wob   = (u16*)p; p += (size_t)HSZ * HSZ * 2;
  u16* cqkv  = (u16*)p; p += (size_t)MROWS * NQKV * 2;
  u16* qb    = (u16*)p; p += (size_t)BB * NH * SS * DH * 2;
  u16* kb    = (u16*)p; p += (size_t)BB * NKV * SS * DH * 2;
  u16* vb    = (u16*)p; p += (size_t)BB * NKV * SS * DH * 2;
  u16* vtb   = (u16*)p; p += (size_t)BB * NKV * SS * DH * 2;
  u16* aob   = (u16*)p; p += (size_t)MROWS * HSZ * 2;

  auto cvt = [&](const float* in, u16* o, size_t n) {
    int n4 = (int)(n / 4);
    cvt_bf16_kernel<<<dim3((n4 + 255) / 256), dim3(256), 0, stream>>>(in, o, n4);
  };
  cvt(x, xb, (size_t)MROWS * HSZ);
  cvt(wq, wqkvb, (size_t)NH * DH * HSZ);
  cvt(wk, wqkvb + (size_t)NH * DH * HSZ, (size_t)NKV * DH * HSZ);
  cvt(wv, wqkvb + (size_t)(NH + NKV) * DH * HSZ, (size_t)NKV * DH * HSZ);
  cvt(wo, wob, (size_t)HSZ * HSZ);

  gemm_bt<u16><<<dim3((MROWS / 128) * (NQKV / 128)), dim3(256), 0, stream>>>(
      xb, wqkvb, cqkv, MROWS, NQKV, HSZ, NQKV / 128);
  postproc_kernel<<<dim3(MROWS), dim3(256), 0, stream>>>(cqkv, cosT, sinT, qw, kw, qb, kb, vb);
  transpose_v_kernel<<<dim3(SS / 64, DH / 64, BB * NKV), dim3(256), 0, stream>>>(vb, vtb);
  attn_kernel<<<dim3(SS / 64, NH, BB), dim3(256), 0, stream>>>(qb, kb, vtb, aob);
  gemm_bt<float><<<dim3((MROWS / 128) * (HSZ / 128)), dim3(256), 0, stream>>>(
      aob, wob, out, MROWS, HSZ, HSZ, HSZ / 128);
}

// Round 2
// 424.041 us; speedup vs baseline: 2.0254x; 2.0254x over previous
//
#include <hip/hip_runtime.h>
#include <hip/hip_bf16.h>
#include <stdint.h>

typedef unsigned short u16;
typedef __attribute__((ext_vector_type(8))) short short8;
typedef __attribute__((ext_vector_type(4))) float f32x4;
typedef __attribute__((ext_vector_type(4))) unsigned short u16x4;

constexpr int BB = 2, SS = 2048, HSZ = 2048, NH = 16, NKV = 4, DH = 128;
constexpr int MROWS = BB * SS;             // 4096
constexpr int NQKV = (NH + 2 * NKV) * DH;  // 3072
constexpr float RMS_EPS = 1e-6f;

__device__ __forceinline__ u16 f2bf(float f) {
  __hip_bfloat16 h = __float2bfloat16(f);
  return *reinterpret_cast<u16*>(&h);
}
__device__ __forceinline__ float bf2f(u16 u) {
  __hip_bfloat16 h;
  *reinterpret_cast<u16*>(&h) = u;
  return __bfloat162float(h);
}

__device__ __forceinline__ void gld16(const void* g, void* l) {
  __builtin_amdgcn_global_load_lds(
      (const __attribute__((address_space(1))) void*)g,
      (__attribute__((address_space(3))) void*)l, 16, 0, 0);
}

// ---------------- fp32 -> bf16 conversion (vectorized) ----------------
__global__ void cvt_bf16_kernel(const float* __restrict__ in, u16* __restrict__ out, int n4) {
  int i = blockIdx.x * blockDim.x + threadIdx.x;
  if (i >= n4) return;
  float4 v = reinterpret_cast<const float4*>(in)[i];
  u16x4 o;
  o.x = f2bf(v.x); o.y = f2bf(v.y); o.z = f2bf(v.z); o.w = f2bf(v.w);
  reinterpret_cast<u16x4*>(out)[i] = o;
}

// ---------------- GEMM: C[M][N] = A[M][K] @ B[N][K]^T (bf16 in, OutT out) ----
// m97 structure: 128x128 tile, BK=32, 4 waves (2x2), global_load_lds width 16.
template <typename OutT>
__global__ __launch_bounds__(256, 2) void gemm_bt(
    const u16* __restrict__ A, const u16* __restrict__ Bm, OutT* __restrict__ C,
    int M, int N, int K, int nbn) {
  __shared__ u16 As[128 * 32];
  __shared__ u16 Bs[128 * 32];
  const int tid = threadIdx.x;
  const int wave = tid >> 6;
  const int lane = tid & 63;
  const int bid = blockIdx.x;
  const int bm = bid / nbn, bn = bid % nbn;
  const int row0 = bm * 128, col0 = bn * 128;
  const int wr = (wave >> 1) * 64, wc = (wave & 1) * 64;
  const int lr = lane & 15, lk = (lane >> 4) * 8;
  const int sr = tid >> 2;        // staging row (0..63) within half-tile
  const int sc = (tid & 3) * 8;   // staging col (elements)

  f32x4 acc[4][4] = {};
  const u16* a0 = A + (size_t)(row0 + sr) * K + sc;
  const u16* a1 = A + (size_t)(row0 + 64 + sr) * K + sc;
  const u16* b0 = Bm + (size_t)(col0 + sr) * K + sc;
  const u16* b1 = Bm + (size_t)(col0 + 64 + sr) * K + sc;
  char* asb = (char*)As + wave * 1024;
  char* bsb = (char*)Bs + wave * 1024;

  for (int k0 = 0; k0 < K; k0 += 32) {
    __syncthreads();
    gld16(a0 + k0, asb);
    gld16(a1 + k0, asb + 4096);
    gld16(b0 + k0, bsb);
    gld16(b1 + k0, bsb + 4096);
    __syncthreads();
    short8 af[4], bfr[4];
#pragma unroll
    for (int m = 0; m < 4; m++)
      af[m] = *(const short8*)&As[(wr + m * 16 + lr) * 32 + lk];
#pragma unroll
    for (int n = 0; n < 4; n++)
      bfr[n] = *(const short8*)&Bs[(wc + n * 16 + lr) * 32 + lk];
#pragma unroll
    for (int m = 0; m < 4; m++)
#pragma unroll
      for (int n = 0; n < 4; n++)
        acc[m][n] = __builtin_amdgcn_mfma_f32_16x16x32_bf16(af[m], bfr[n], acc[m][n], 0, 0, 0);
  }
  const int cr = (lane >> 4) * 4, cc = lane & 15;
#pragma unroll
  for (int m = 0; m < 4; m++) {
#pragma unroll
    for (int n = 0; n < 4; n++) {
#pragma unroll
      for (int r = 0; r < 4; r++) {
        size_t idx = (size_t)(row0 + wr + m * 16 + cr + r) * N + (col0 + wc + n * 16 + cc);
        if constexpr (sizeof(OutT) == 2) C[idx] = (OutT)f2bf(acc[m][n][r]);
        else C[idx] = acc[m][n][r];
      }
    }
  }
}

// ---------------- RMS-norm (q,k heads) + RoPE + split/cast --------------------
// One block per (b,s) row of C_qkv[4096][3072]; wave handles heads wave,wave+4,...
// Q heads get the attention scale D^-0.5 folded in.
__global__ __launch_bounds__(256) void postproc_kernel(
    const u16* __restrict__ Cqkv, const float* __restrict__ cosT,
    const float* __restrict__ sinT, const float* __restrict__ qw,
    const float* __restrict__ kw, u16* __restrict__ qO, u16* __restrict__ kO,
    u16* __restrict__ vO) {
  const int row = blockIdx.x;
  const int b = row / SS, s = row % SS;
  const int wave = threadIdx.x >> 6, lane = threadIdx.x & 63;
  const u16* base = Cqkv + (size_t)row * NQKV;
  const int d0 = lane * 2;
  const float ATT_SCALE = 0.08838834764831843f;  // D^-0.5
  for (int hd = wave; hd < NH + 2 * NKV; hd += 4) {
    const u16* hp = base + hd * DH;
    ushort2 raw = *(const ushort2*)(hp + d0);
    if (hd < NH + NKV) {
      float v0 = bf2f(raw.x), v1 = bf2f(raw.y);
      float ss = v0 * v0 + v1 * v1;
#pragma unroll
      for (int off = 32; off > 0; off >>= 1) ss += __shfl_xor(ss, off);
      float inv = rsqrtf(ss * (1.0f / DH) + RMS_EPS);
      const float* w = (hd < NH) ? qw : kw;
      float n0 = v0 * inv * w[d0], n1 = v1 * inv * w[d0 + 1];
      // rotate_half: lane<32 holds d<64, partner lane^32 holds d^64
      float r0 = __shfl_xor(n0, 32), r1 = __shfl_xor(n1, 32);
      float sgn = (lane < 32) ? -1.f : 1.f;
      float c0 = cosT[s * DH + d0], c1 = cosT[s * DH + d0 + 1];
      float s0 = sinT[s * DH + d0], s1 = sinT[s * DH + d0 + 1];
      float o0 = n0 * c0 + sgn * r0 * s0;
      float o1 = n1 * c1 + sgn * r1 * s1;
      ushort2 o;
      if (hd < NH) {
        o.x = f2bf(o0 * ATT_SCALE);
        o.y = f2bf(o1 * ATT_SCALE);
        *(ushort2*)(qO + ((size_t)((b * NH + hd) * SS + s)) * DH + d0) = o;
      } else {
        o.x = f2bf(o0);
        o.y = f2bf(o1);
        *(ushort2*)(kO + ((size_t)((b * NKV + hd - NH) * SS + s)) * DH + d0) = o;
      }
    } else {
      *(ushort2*)(vO + ((size_t)((b * NKV + hd - NH - NKV) * SS + s)) * DH + d0) = raw;
    }
  }
}

// ---------------- V transpose: [b,hkv][S][D] -> [b,hkv][D][S] ----------------
__global__ __launch_bounds__(256) void transpose_v_kernel(const u16* __restrict__ v,
                                                          u16* __restrict__ vt) {
  __shared__ u16 tile[64][68];  // pad to 68 for bank spread + 8B alignment
  const int bh = blockIdx.z;
  const int st = blockIdx.x * 64;
  const int dt = blockIdx.y * 64;
  const int tid = threadIdx.x;
  const u16* src = v + ((size_t)bh * SS + st) * DH + dt;
#pragma unroll
  for (int it = 0; it < 4; it++) {
    int r = (tid >> 4) + it * 16, c = (tid & 15) * 4;
    *(u16x4*)&tile[r][c] = *(const u16x4*)(src + (size_t)r * DH + c);
  }
  __syncthreads();
  u16* dst = vt + ((size_t)bh * DH + dt) * SS + st;
#pragma unroll
  for (int it = 0; it < 4; it++) {
    int r2 = (tid >> 4) + it * 16, c2 = (tid & 15) * 4;
    u16x4 o;
    o.x = tile[c2][r2]; o.y = tile[c2 + 1][r2];
    o.z = tile[c2 + 2][r2]; o.w = tile[c2 + 3][r2];
    *(u16x4*)(dst + (size_t)r2 * SS + c2) = o;
  }
}

// ---------------- causal GQA flash attention ---------------------------------
// grid (S/64, H, B); 4 waves; wave owns 16 q-rows; KV tiles of 64.
// K[64][128] and Vt[128][64] staged in LDS (XOR-swizzled), shared by all waves.
// T14 async-STAGE: issue tile t+1 global loads before computing tile t;
// ds_write after the post-compute barrier.
__global__ __launch_bounds__(256, 3) void attn_kernel(
    const u16* __restrict__ Q, const u16* __restrict__ Kb,
    const u16* __restrict__ Vt, u16* __restrict__ O) {
  __shared__ __align__(16) u16 Ks[64 * 128];
  __shared__ __align__(16) u16 Vs[128 * 64];
  __shared__ u16 Plds[4][16 * 72];  // per-wave P transpose buffer (stride 72)
  const int qt = blockIdx.x, h = blockIdx.y, b = blockIdx.z;
  const int hkv = h >> 2;
  const int tid = threadIdx.x;
  const int wave = tid >> 6, lane = tid & 63;
  const int q0 = qt * 64 + wave * 16;
  const int lr = lane & 15, lk = lane >> 4;
  const u16* qbase = Q + ((size_t)(b * NH + h) * SS) * DH;
  const u16* kbase = Kb + ((size_t)(b * NKV + hkv) * SS) * DH;
  const u16* vbase = Vt + ((size_t)(b * NKV + hkv) * DH) * SS;

  // staging geometry (reg-staged so LDS writes can be XOR-swizzled)
  const int krow = tid >> 4;                       // 0..15 (+16*i)
  const int kcol = (tid & 15) * 8;                 // element col in 128-wide row
  const int kswz = kcol ^ ((krow & 7) << 3);       // 16B-block XOR swizzle
  const int vrow = tid >> 3;                       // 0..31 (+32*i)
  const int vcol = (tid & 7) * 8;                  // element col in 64-wide row
  const int vswz = vcol ^ ((vrow & 7) << 3);
  const int kx = (lr & 7) << 3;                    // read-side XOR (elements)

  short8 qf[4];
#pragma unroll
  for (int c = 0; c < 4; c++)
    qf[c] = *(const short8*)(qbase + (size_t)(q0 + lr) * DH + c * 32 + lk * 8);

  f32x4 o_acc[8] = {};
  float m_run[4], l_run[4];
#pragma unroll
  for (int r = 0; r < 4; r++) { m_run[r] = -1e30f; l_run[r] = 0.f; }

  u16* pl = &Plds[wave][0];
  const int nt = qt + 1;  // uniform across the block; causality via mask

  int4 kr0, kr1, kr2, kr3, vr0, vr1, vr2, vr3;
#define STAGE_LOAD(T)                                                         \
  {                                                                           \
    const int kv0_ = (T) * 64;                                                \
    kr0 = *(const int4*)(kbase + (size_t)(kv0_ + krow) * DH + kcol);          \
    kr1 = *(const int4*)(kbase + (size_t)(kv0_ + krow + 16) * DH + kcol);     \
    kr2 = *(const int4*)(kbase + (size_t)(kv0_ + krow + 32) * DH + kcol);     \
    kr3 = *(const int4*)(kbase + (size_t)(kv0_ + krow + 48) * DH + kcol);     \
    vr0 = *(const int4*)(vbase + (size_t)(vrow) * SS + kv0_ + vcol);          \
    vr1 = *(const int4*)(vbase + (size_t)(vrow + 32) * SS + kv0_ + vcol);     \
    vr2 = *(const int4*)(vbase + (size_t)(vrow + 64) * SS + kv0_ + vcol);     \
    vr3 = *(const int4*)(vbase + (size_t)(vrow + 96) * SS + kv0_ + vcol);     \
  }
#define STAGE_WRITE()                                                         \
  {                                                                           \
    *(int4*)&Ks[(krow) * DH + kswz] = kr0;                                    \
    *(int4*)&Ks[(krow + 16) * DH + kswz] = kr1;                               \
    *(int4*)&Ks[(krow + 32) * DH + kswz] = kr2;                               \
    *(int4*)&Ks[(krow + 48) * DH + kswz] = kr3;                               \
    *(int4*)&Vs[(vrow) * 64 + vswz] = vr0;                                    \
    *(int4*)&Vs[(vrow + 32) * 64 + vswz] = vr1;                               \
    *(int4*)&Vs[(vrow + 64) * 64 + vswz] = vr2;                               \
    *(int4*)&Vs[(vrow + 96) * 64 + vswz] = vr3;                               \
  }

  STAGE_LOAD(0);
  STAGE_WRITE();
  __syncthreads();

  for (int t = 0; t < nt; t++) {
    const int kv0 = t * 64;
    if (t + 1 < nt) STAGE_LOAD(t + 1);  // in-flight under compute (T14)

    // ---- QK^T: S[16 q][64 kv] from LDS (swizzled reads) ----
    f32x4 sf[4] = {};
#pragma unroll
    for (int n = 0; n < 4; n++) {
#pragma unroll
      for (int c = 0; c < 4; c++) {
        short8 kf = *(const short8*)&Ks[(n * 16 + lr) * DH + ((c * 32 + lk * 8) ^ kx)];
        sf[n] = __builtin_amdgcn_mfma_f32_16x16x32_bf16(qf[c], kf, sf[n], 0, 0, 0);
      }
    }
    // ---- online softmax (C-frag: row = lk*4+r, col = n*16+lr) ----
    const int qrow = q0 + lk * 4;
    float p[4][4];
#pragma unroll
    for (int r = 0; r < 4; r++) {
      float mx = -1e30f;
#pragma unroll
      for (int n = 0; n < 4; n++) {
        float sv = sf[n][r];
        sv = (kv0 + n * 16 + lr <= qrow + r) ? sv : -1e30f;
        p[n][r] = sv;
        mx = fmaxf(mx, sv);
      }
      mx = fmaxf(mx, __shfl_xor(mx, 1));
      mx = fmaxf(mx, __shfl_xor(mx, 2));
      mx = fmaxf(mx, __shfl_xor(mx, 4));
      mx = fmaxf(mx, __shfl_xor(mx, 8));
      const float mnew = fmaxf(m_run[r], mx);
      const float alpha = __expf(m_run[r] - mnew);
      m_run[r] = mnew;
      float rs = 0.f;
#pragma unroll
      for (int n = 0; n < 4; n++) {
        float e = __expf(p[n][r] - mnew);
        p[n][r] = e;
        rs += e;
      }
      rs += __shfl_xor(rs, 1);
      rs += __shfl_xor(rs, 2);
      rs += __shfl_xor(rs, 4);
      rs += __shfl_xor(rs, 8);
      l_run[r] = l_run[r] * alpha + rs;
#pragma unroll
      for (int n2 = 0; n2 < 8; n2++) o_acc[n2][r] *= alpha;
    }
    // ---- P: C-layout -> A-layout via wave-private LDS ----
#pragma unroll
    for (int r = 0; r < 4; r++)
#pragma unroll
      for (int n = 0; n < 4; n++)
        pl[(lk * 4 + r) * 72 + n * 16 + lr] = f2bf(p[n][r]);
    // ---- PV: O[16 q][128 d] += P[16][64] @ V[64][128], V^T from LDS ----
#pragma unroll
    for (int c2 = 0; c2 < 2; c2++) {
      short8 pf = *(const short8*)&pl[lr * 72 + c2 * 32 + lk * 8];
#pragma unroll
      for (int n2 = 0; n2 < 8; n2++) {
        short8 vf = *(const short8*)&Vs[(n2 * 16 + lr) * 64 + ((c2 * 32 + lk * 8) ^ kx)];
        o_acc[n2] = __builtin_amdgcn_mfma_f32_16x16x32_bf16(pf, vf, o_acc[n2], 0, 0, 0);
      }
    }
    __syncthreads();                      // all waves done reading Ks/Vs
    if (t + 1 < nt) STAGE_WRITE();        // compiler inserts vmcnt wait here
    __syncthreads();                      // staged tile visible
  }
#undef STAGE_LOAD
#undef STAGE_WRITE

  // ---- epilogue: normalize, write O[b][s][h*128+d] bf16 ----
  const int cr = lk * 4;
#pragma unroll
  for (int r = 0; r < 4; r++) {
    const float inv = 1.0f / l_run[r];
    u16* orow = O + ((size_t)(b * SS + q0 + cr + r)) * (NH * DH) + h * DH;
#pragma unroll
    for (int n2 = 0; n2 < 8; n2++) orow[n2 * 16 + lr] = f2bf(o_acc[n2][r] * inv);
  }
}

// -----------------------------------------------------------------------------
extern "C" void kernel_launch(void* const* d_in, const int* in_sizes, int n_in,
                              void* d_out, int out_size, void* d_ws, size_t ws_size,
                              hipStream_t stream) {
  const float* x    = (const float*)d_in[0];
  const float* cosT = (const float*)d_in[1];
  const float* sinT = (const float*)d_in[2];
  // d_in[3] = mask (causal, reconstructed analytically)
  const float* wq = (const float*)d_in[4];
  const float* wk = (const float*)d_in[5];
  const float* wv = (const float*)d_in[6];
  const float* wo = (const float*)d_in[7];
  const float* qw = (const float*)d_in[8];
  const float* kw = (const float*)d_in[9];
  float* out = (float*)d_out;

  char* p = (char*)d_ws;
  u16* xb    = (u16*)p; p += (size_t)MROWS * HSZ * 2;
  u16* wqkvb = (u16*)p; p += (size_t)NQKV * HSZ * 2;
  u16* wob   = (u16*)p; p += (size_t)HSZ * HSZ * 2;
  u16* cqkv  = (u16*)p; p += (size_t)MROWS * NQKV * 2;
  u16* qb    = (u16*)p; p += (size_t)BB * NH * SS * DH * 2;
  u16* kb    = (u16*)p; p += (size_t)BB * NKV * SS * DH * 2;
  u16* vb    = (u16*)p; p += (size_t)BB * NKV * SS * DH * 2;
  u16* vtb   = (u16*)p; p += (size_t)BB * NKV * SS * DH * 2;
  u16* aob   = (u16*)p; p += (size_t)MROWS * HSZ * 2;

  auto cvt = [&](const float* in, u16* o, size_t n) {
    int n4 = (int)(n / 4);
    cvt_bf16_kernel<<<dim3((n4 + 255) / 256), dim3(256), 0, stream>>>(in, o, n4);
  };
  cvt(x, xb, (size_t)MROWS * HSZ);
  cvt(wq, wqkvb, (size_t)NH * DH * HSZ);
  cvt(wk, wqkvb + (size_t)NH * DH * HSZ, (size_t)NKV * DH * HSZ);
  cvt(wv, wqkvb + (size_t)(NH + NKV) * DH * HSZ, (size_t)NKV * DH * HSZ);
  cvt(wo, wob, (size_t)HSZ * HSZ);

  gemm_bt<u16><<<dim3((MROWS / 128) * (NQKV / 128)), dim3(256), 0, stream>>>(
      xb, wqkvb, cqkv, MROWS, NQKV, HSZ, NQKV / 128);
  postproc_kernel<<<dim3(MROWS), dim3(256), 0, stream>>>(cqkv, cosT, sinT, qw, kw, qb, kb, vb);
  transpose_v_kernel<<<dim3(SS / 64, DH / 64, BB * NKV), dim3(256), 0, stream>>>(vb, vtb);
  attn_kernel<<<dim3(SS / 64, NH, BB), dim3(256), 0, stream>>>(qb, kb, vtb, aob);
  gemm_bt<float><<<dim3((MROWS / 128) * (HSZ / 128)), dim3(256), 0, stream>>>(
      aob, wob, out, MROWS, HSZ, HSZ, HSZ / 128);
}

// Round 3
// 341.296 us; speedup vs baseline: 2.5164x; 1.2424x over previous
//
#include <hip/hip_runtime.h>
#include <hip/hip_bf16.h>
#include <stdint.h>

typedef unsigned short u16;
typedef __attribute__((ext_vector_type(8))) short short8;
typedef __attribute__((ext_vector_type(4))) float f32x4;
typedef __attribute__((ext_vector_type(4))) unsigned short u16x4;

constexpr int BB = 2, SS = 2048, HSZ = 2048, NH = 16, NKV = 4, DH = 128;
constexpr int MROWS = BB * SS;             // 4096
constexpr int NQKV = (NH + 2 * NKV) * DH;  // 3072
constexpr float RMS_EPS = 1e-6f;

__device__ __forceinline__ u16 f2bf(float f) {
  __hip_bfloat16 h = __float2bfloat16(f);
  return *reinterpret_cast<u16*>(&h);
}
__device__ __forceinline__ float bf2f(u16 u) {
  __hip_bfloat16 h;
  *reinterpret_cast<u16*>(&h) = u;
  return __bfloat162float(h);
}

__device__ __forceinline__ void gld16(const void* g, void* l) {
  __builtin_amdgcn_global_load_lds(
      (const __attribute__((address_space(1))) void*)g,
      (__attribute__((address_space(3))) void*)l, 16, 0, 0);
}

// ---------------- fp32 -> bf16 conversion (vectorized) ----------------
__global__ void cvt_bf16_kernel(const float* __restrict__ in, u16* __restrict__ out, int n4) {
  int i = blockIdx.x * blockDim.x + threadIdx.x;
  if (i >= n4) return;
  float4 v = reinterpret_cast<const float4*>(in)[i];
  u16x4 o;
  o.x = f2bf(v.x); o.y = f2bf(v.y); o.z = f2bf(v.z); o.w = f2bf(v.w);
  reinterpret_cast<u16x4*>(out)[i] = o;
}

// ---------------- GEMM: C[M][N] = A[M][K] @ B[N][K]^T (bf16 in, OutT out) ----
// m97 structure: 128x128 tile, BK=32, 4 waves (2x2), global_load_lds width 16.
template <typename OutT>
__global__ __launch_bounds__(256, 2) void gemm_bt(
    const u16* __restrict__ A, const u16* __restrict__ Bm, OutT* __restrict__ C,
    int M, int N, int K, int nbn) {
  __shared__ u16 As[128 * 32];
  __shared__ u16 Bs[128 * 32];
  const int tid = threadIdx.x;
  const int wave = tid >> 6;
  const int lane = tid & 63;
  const int bid = blockIdx.x;
  const int bm = bid / nbn, bn = bid % nbn;
  const int row0 = bm * 128, col0 = bn * 128;
  const int wr = (wave >> 1) * 64, wc = (wave & 1) * 64;
  const int lr = lane & 15, lk = (lane >> 4) * 8;
  const int sr = tid >> 2;        // staging row (0..63) within half-tile
  const int sc = (tid & 3) * 8;   // staging col (elements)

  f32x4 acc[4][4] = {};
  const u16* a0 = A + (size_t)(row0 + sr) * K + sc;
  const u16* a1 = A + (size_t)(row0 + 64 + sr) * K + sc;
  const u16* b0 = Bm + (size_t)(col0 + sr) * K + sc;
  const u16* b1 = Bm + (size_t)(col0 + 64 + sr) * K + sc;
  char* asb = (char*)As + wave * 1024;
  char* bsb = (char*)Bs + wave * 1024;

  for (int k0 = 0; k0 < K; k0 += 32) {
    __syncthreads();
    gld16(a0 + k0, asb);
    gld16(a1 + k0, asb + 4096);
    gld16(b0 + k0, bsb);
    gld16(b1 + k0, bsb + 4096);
    __syncthreads();
    short8 af[4], bfr[4];
#pragma unroll
    for (int m = 0; m < 4; m++)
      af[m] = *(const short8*)&As[(wr + m * 16 + lr) * 32 + lk];
#pragma unroll
    for (int n = 0; n < 4; n++)
      bfr[n] = *(const short8*)&Bs[(wc + n * 16 + lr) * 32 + lk];
#pragma unroll
    for (int m = 0; m < 4; m++)
#pragma unroll
      for (int n = 0; n < 4; n++)
        acc[m][n] = __builtin_amdgcn_mfma_f32_16x16x32_bf16(af[m], bfr[n], acc[m][n], 0, 0, 0);
  }
  const int cr = (lane >> 4) * 4, cc = lane & 15;
#pragma unroll
  for (int m = 0; m < 4; m++) {
#pragma unroll
    for (int n = 0; n < 4; n++) {
#pragma unroll
      for (int r = 0; r < 4; r++) {
        size_t idx = (size_t)(row0 + wr + m * 16 + cr + r) * N + (col0 + wc + n * 16 + cc);
        if constexpr (sizeof(OutT) == 2) C[idx] = (OutT)f2bf(acc[m][n][r]);
        else C[idx] = acc[m][n][r];
      }
    }
  }
}

// ---------------- RMS-norm (q,k heads) + RoPE + split/cast --------------------
// One block per (b,s) row of C_qkv[4096][3072]; wave handles heads wave,wave+4,...
// Q heads get D^-0.5 * log2(e) folded in (attn uses exp2 with static max).
__global__ __launch_bounds__(256) void postproc_kernel(
    const u16* __restrict__ Cqkv, const float* __restrict__ cosT,
    const float* __restrict__ sinT, const float* __restrict__ qw,
    const float* __restrict__ kw, u16* __restrict__ qO, u16* __restrict__ kO,
    u16* __restrict__ vO) {
  const int row = blockIdx.x;
  const int b = row / SS, s = row % SS;
  const int wave = threadIdx.x >> 6, lane = threadIdx.x & 63;
  const u16* base = Cqkv + (size_t)row * NQKV;
  const int d0 = lane * 2;
  const float ATT_SCALE = 0.08838834764831843f * 1.4426950408889634f;  // D^-0.5 * log2e
  for (int hd = wave; hd < NH + 2 * NKV; hd += 4) {
    const u16* hp = base + hd * DH;
    ushort2 raw = *(const ushort2*)(hp + d0);
    if (hd < NH + NKV) {
      float v0 = bf2f(raw.x), v1 = bf2f(raw.y);
      float ss = v0 * v0 + v1 * v1;
#pragma unroll
      for (int off = 32; off > 0; off >>= 1) ss += __shfl_xor(ss, off);
      float inv = rsqrtf(ss * (1.0f / DH) + RMS_EPS);
      const float* w = (hd < NH) ? qw : kw;
      float n0 = v0 * inv * w[d0], n1 = v1 * inv * w[d0 + 1];
      // rotate_half: lane<32 holds d<64, partner lane^32 holds d^64
      float r0 = __shfl_xor(n0, 32), r1 = __shfl_xor(n1, 32);
      float sgn = (lane < 32) ? -1.f : 1.f;
      float c0 = cosT[s * DH + d0], c1 = cosT[s * DH + d0 + 1];
      float s0 = sinT[s * DH + d0], s1 = sinT[s * DH + d0 + 1];
      float o0 = n0 * c0 + sgn * r0 * s0;
      float o1 = n1 * c1 + sgn * r1 * s1;
      ushort2 o;
      if (hd < NH) {
        o.x = f2bf(o0 * ATT_SCALE);
        o.y = f2bf(o1 * ATT_SCALE);
        *(ushort2*)(qO + ((size_t)((b * NH + hd) * SS + s)) * DH + d0) = o;
      } else {
        o.x = f2bf(o0);
        o.y = f2bf(o1);
        *(ushort2*)(kO + ((size_t)((b * NKV + hd - NH) * SS + s)) * DH + d0) = o;
      }
    } else {
      *(ushort2*)(vO + ((size_t)((b * NKV + hd - NH - NKV) * SS + s)) * DH + d0) = raw;
    }
  }
}

// ---------------- V transpose: [b,hkv][S][D] -> [b,hkv][D][S] ----------------
__global__ __launch_bounds__(256) void transpose_v_kernel(const u16* __restrict__ v,
                                                          u16* __restrict__ vt) {
  __shared__ u16 tile[64][68];  // pad to 68 for bank spread + 8B alignment
  const int bh = blockIdx.z;
  const int st = blockIdx.x * 64;
  const int dt = blockIdx.y * 64;
  const int tid = threadIdx.x;
  const u16* src = v + ((size_t)bh * SS + st) * DH + dt;
#pragma unroll
  for (int it = 0; it < 4; it++) {
    int r = (tid >> 4) + it * 16, c = (tid & 15) * 4;
    *(u16x4*)&tile[r][c] = *(const u16x4*)(src + (size_t)r * DH + c);
  }
  __syncthreads();
  u16* dst = vt + ((size_t)bh * DH + dt) * SS + st;
#pragma unroll
  for (int it = 0; it < 4; it++) {
    int r2 = (tid >> 4) + it * 16, c2 = (tid & 15) * 4;
    u16x4 o;
    o.x = tile[c2][r2]; o.y = tile[c2 + 1][r2];
    o.z = tile[c2 + 2][r2]; o.w = tile[c2 + 3][r2];
    *(u16x4*)(dst + (size_t)r2 * SS + c2) = o;
  }
}

// ---------------- causal GQA flash attention ---------------------------------
// grid (S/128 pairs, H, B); 4 waves; wave owns 16 q-rows; KV tiles of 64.
// Block processes q-tiles {pid, 31-pid} sequentially -> uniform 33 tile-units.
// Swapped QK^T (mfma(K,Q)): lane holds S^T[kv=(l>>4)*4+r+16n][q=l&15] ->
// softmax row-sum = in-lane + 2 shfl. Static max (|S|<=sqrt(D)=11.31, exact:
// RMS-normed q,k + RoPE rotation): p = exp2(S' - 12*log2e), no rescale.
__global__ __launch_bounds__(256, 2) void attn_kernel(
    const u16* __restrict__ Q, const u16* __restrict__ Kb,
    const u16* __restrict__ Vt, u16* __restrict__ O) {
  __shared__ __align__(16) u16 Ks[64 * 128];
  __shared__ __align__(16) u16 Vs[128 * 64];
  __shared__ __align__(16) u16 Plds[4][16 * 64];  // per-wave P buffer (2KB)
  const int pid = blockIdx.x, h = blockIdx.y, b = blockIdx.z;
  const int hkv = h >> 2;
  const int tid = threadIdx.x;
  const int wave = tid >> 6, lane = tid & 63;
  const int lr = lane & 15, g = lane >> 4;
  const u16* qbase = Q + ((size_t)(b * NH + h) * SS) * DH;
  const u16* kbase = Kb + ((size_t)(b * NKV + hkv) * SS) * DH;
  const u16* vbase = Vt + ((size_t)(b * NKV + hkv) * DH) * SS;

  // staging geometry (reg-staged so LDS writes can be XOR-swizzled)
  const int krow = tid >> 4;                       // 0..15 (+16*i)
  const int kcol = (tid & 15) * 8;                 // element col in 128-wide row
  const int kswz = kcol ^ ((krow & 7) << 3);       // 16B-block XOR swizzle
  const int vrow = tid >> 3;                       // 0..31 (+32*i)
  const int vcol = (tid & 7) * 8;                  // element col in 64-wide row
  const int vswz = vcol ^ ((vrow & 7) << 3);
  const int kx = (lr & 7) << 3;                    // read-side XOR (elements)
  const int psw = (lr & 7) << 4;                   // Plds byte XOR (row period 128B)
  char* pl = (char*)&Plds[wave][0];

  int4 kr0, kr1, kr2, kr3, vr0, vr1, vr2, vr3;
#define STAGE_LOAD(T)                                                         \
  {                                                                           \
    const int kv0_ = (T) * 64;                                                \
    kr0 = *(const int4*)(kbase + (size_t)(kv0_ + krow) * DH + kcol);          \
    kr1 = *(const int4*)(kbase + (size_t)(kv0_ + krow + 16) * DH + kcol);     \
    kr2 = *(const int4*)(kbase + (size_t)(kv0_ + krow + 32) * DH + kcol);     \
    kr3 = *(const int4*)(kbase + (size_t)(kv0_ + krow + 48) * DH + kcol);     \
    vr0 = *(const int4*)(vbase + (size_t)(vrow) * SS + kv0_ + vcol);          \
    vr1 = *(const int4*)(vbase + (size_t)(vrow + 32) * SS + kv0_ + vcol);     \
    vr2 = *(const int4*)(vbase + (size_t)(vrow + 64) * SS + kv0_ + vcol);     \
    vr3 = *(const int4*)(vbase + (size_t)(vrow + 96) * SS + kv0_ + vcol);     \
  }
#define STAGE_WRITE()                                                         \
  {                                                                           \
    *(int4*)&Ks[(krow) * DH + kswz] = kr0;                                    \
    *(int4*)&Ks[(krow + 16) * DH + kswz] = kr1;                               \
    *(int4*)&Ks[(krow + 32) * DH + kswz] = kr2;                               \
    *(int4*)&Ks[(krow + 48) * DH + kswz] = kr3;                               \
    *(int4*)&Vs[(vrow) * 64 + vswz] = vr0;                                    \
    *(int4*)&Vs[(vrow + 32) * 64 + vswz] = vr1;                               \
    *(int4*)&Vs[(vrow + 64) * 64 + vswz] = vr2;                               \
    *(int4*)&Vs[(vrow + 96) * 64 + vswz] = vr3;                               \
  }

#pragma unroll 1
  for (int half = 0; half < 2; half++) {
    const int qt = half ? (SS / 64 - 1 - pid) : pid;
    const int q0 = qt * 64 + wave * 16;
    const int nt = qt + 1;  // uniform across block

    short8 qf[4];
#pragma unroll
    for (int c = 0; c < 4; c++)
      qf[c] = *(const short8*)(qbase + (size_t)(q0 + lr) * DH + c * 32 + g * 8);

    f32x4 o_acc[8] = {};
    float l_run = 0.f;

    STAGE_LOAD(0);
    STAGE_WRITE();
    __syncthreads();

    for (int t = 0; t < nt; t++) {
      const int kv0 = t * 64;
      if (t + 1 < nt) STAGE_LOAD(t + 1);  // in-flight under compute (T14)

      // ---- swapped QK^T: S^T[64 kv][16 q] (A=K, B=Q; fragments identical) ----
      f32x4 sf[4] = {};
      __builtin_amdgcn_s_setprio(1);
#pragma unroll
      for (int n = 0; n < 4; n++) {
#pragma unroll
        for (int c = 0; c < 4; c++) {
          short8 kf = *(const short8*)&Ks[(n * 16 + lr) * DH + ((c * 32 + g * 8) ^ kx)];
          sf[n] = __builtin_amdgcn_mfma_f32_16x16x32_bf16(kf, qf[c], sf[n], 0, 0, 0);
        }
      }
      __builtin_amdgcn_s_setprio(0);

      // ---- softmax, static max: lane holds S[kv=16n+4g+r][q=q0+lr] ----
      const int qabs = q0 + lr;
      float p[4][4];
      float rs = 0.f;
#pragma unroll
      for (int n = 0; n < 4; n++) {
#pragma unroll
        for (int r = 0; r < 4; r++) {
          const int kvabs = kv0 + n * 16 + g * 4 + r;
          float e = exp2f(sf[n][r] - 17.312340490667562f);  // 12*log2e
          e = (kvabs <= qabs) ? e : 0.f;
          p[n][r] = e;
          rs += e;
        }
      }
      rs += __shfl_xor(rs, 16);
      rs += __shfl_xor(rs, 32);
      l_run += rs;

      // ---- pack P -> bf16, wave-private LDS (vectorized, swizzled) ----
#pragma unroll
      for (int n = 0; n < 4; n++) {
        uint2 wv;
        wv.x = (unsigned)f2bf(p[n][0]) | ((unsigned)f2bf(p[n][1]) << 16);
        wv.y = (unsigned)f2bf(p[n][2]) | ((unsigned)f2bf(p[n][3]) << 16);
        *(uint2*)(pl + lr * 128 + ((32 * n + 8 * g) ^ psw)) = wv;
      }

      // ---- PV: O[16 q][128 d] += P[16][64] @ V[64][128] ----
      __builtin_amdgcn_s_setprio(1);
#pragma unroll
      for (int c2 = 0; c2 < 2; c2++) {
        short8 pf = *(const short8*)(pl + lr * 128 + ((64 * c2 + 16 * g) ^ psw));
#pragma unroll
        for (int n2 = 0; n2 < 8; n2++) {
          short8 vf = *(const short8*)&Vs[(n2 * 16 + lr) * 64 + ((c2 * 32 + g * 8) ^ kx)];
          o_acc[n2] = __builtin_amdgcn_mfma_f32_16x16x32_bf16(pf, vf, o_acc[n2], 0, 0, 0);
        }
      }
      __builtin_amdgcn_s_setprio(0);

      __syncthreads();                      // all waves done reading Ks/Vs
      if (t + 1 < nt) STAGE_WRITE();        // compiler inserts vmcnt wait here
      __syncthreads();                      // staged tile visible
    }

    // ---- epilogue: O row = g*4+r (PV C-layout); l lives in lane (.&15)==row ----
#pragma unroll
    for (int r = 0; r < 4; r++) {
      const float ls = __shfl(l_run, (g << 4) | (g * 4 + r));
      const float inv = 1.0f / ls;
      u16* orow = O + ((size_t)(b * SS + q0 + g * 4 + r)) * (NH * DH) + h * DH;
#pragma unroll
      for (int n2 = 0; n2 < 8; n2++) orow[n2 * 16 + lr] = f2bf(o_acc[n2][r] * inv);
    }
  }
#undef STAGE_LOAD
#undef STAGE_WRITE
}

// -----------------------------------------------------------------------------
extern "C" void kernel_launch(void* const* d_in, const int* in_sizes, int n_in,
                              void* d_out, int out_size, void* d_ws, size_t ws_size,
                              hipStream_t stream) {
  const float* x    = (const float*)d_in[0];
  const float* cosT = (const float*)d_in[1];
  const float* sinT = (const float*)d_in[2];
  // d_in[3] = mask (causal, reconstructed analytically)
  const float* wq = (const float*)d_in[4];
  const float* wk = (const float*)d_in[5];
  const float* wv = (const float*)d_in[6];
  const float* wo = (const float*)d_in[7];
  const float* qw = (const float*)d_in[8];
  const float* kw = (const float*)d_in[9];
  float* out = (float*)d_out;

  char* p = (char*)d_ws;
  u16* xb    = (u16*)p; p += (size_t)MROWS * HSZ * 2;
  u16* wqkvb = (u16*)p; p += (size_t)NQKV * HSZ * 2;
  u16* wob   = (u16*)p; p += (size_t)HSZ * HSZ * 2;
  u16* cqkv  = (u16*)p; p += (size_t)MROWS * NQKV * 2;
  u16* qb    = (u16*)p; p += (size_t)BB * NH * SS * DH * 2;
  u16* kb    = (u16*)p; p += (size_t)BB * NKV * SS * DH * 2;
  u16* vb    = (u16*)p; p += (size_t)BB * NKV * SS * DH * 2;
  u16* vtb   = (u16*)p; p += (size_t)BB * NKV * SS * DH * 2;
  u16* aob   = (u16*)p; p += (size_t)MROWS * HSZ * 2;

  auto cvt = [&](const float* in, u16* o, size_t n) {
    int n4 = (int)(n / 4);
    cvt_bf16_kernel<<<dim3((n4 + 255) / 256), dim3(256), 0, stream>>>(in, o, n4);
  };
  cvt(x, xb, (size_t)MROWS * HSZ);
  cvt(wq, wqkvb, (size_t)NH * DH * HSZ);
  cvt(wk, wqkvb + (size_t)NH * DH * HSZ, (size_t)NKV * DH * HSZ);
  cvt(wv, wqkvb + (size_t)(NH + NKV) * DH * HSZ, (size_t)NKV * DH * HSZ);
  cvt(wo, wob, (size_t)HSZ * HSZ);

  gemm_bt<u16><<<dim3((MROWS / 128) * (NQKV / 128)), dim3(256), 0, stream>>>(
      xb, wqkvb, cqkv, MROWS, NQKV, HSZ, NQKV / 128);
  postproc_kernel<<<dim3(MROWS), dim3(256), 0, stream>>>(cqkv, cosT, sinT, qw, kw, qb, kb, vb);
  transpose_v_kernel<<<dim3(SS / 64, DH / 64, BB * NKV), dim3(256), 0, stream>>>(vb, vtb);
  attn_kernel<<<dim3(SS / 128, NH, BB), dim3(256), 0, stream>>>(qb, kb, vtb, aob);
  gemm_bt<float><<<dim3((MROWS / 128) * (HSZ / 128)), dim3(256), 0, stream>>>(
      aob, wob, out, MROWS, HSZ, HSZ, HSZ / 128);
}